// Round 12
// baseline (280.416 us; speedup 1.0000x reference)
//
#include <hip/hip_runtime.h>
#include <hip/hip_bf16.h>
#include <math.h>

#define BB 4
#define NN 4096
#define KK 32
#define HH 128

#define NPB 32        // nodes per block
#define THREADS 512   // 8 waves, 4 nodes per wave
#define NPI (NPB / 8) // nodes per wave

typedef short bf16x8 __attribute__((ext_vector_type(8)));
typedef float f32x16 __attribute__((ext_vector_type(16)));
typedef unsigned int u32;

// LDS map (73.25 KB -> 2 blocks/CU = 16 waves/CU = 4 waves/SIMD).
// H0 staged in LDS (the ONLY no-spill structure, r8 vs r9/r10/r11);
// W1/W2 frag tables moved to GLOBAL (L1/L2-resident, shared by all blocks).
#define OFF_H0   0                          // 8 waves x 8 ks x 64 lanes x 16 B = 65536 B
#define OFF_SELF 65536                      // 32 nodes x 128 bf16 = 8192 B
#define OFF_WD   (OFF_SELF + NPB*HH*2)      // 256 B
#define OFF_B1   (OFF_WD + HH*2)            // 512 B (f32 b1)
#define OFF_B2   (OFF_B1 + HH*4)            // 512 B (f32 b2)
#define LDS_TOTAL (OFF_B2 + HH*4)           // 75008 B

#define MFMA(a,b,c) __builtin_amdgcn_mfma_f32_32x32x16_bf16(a,b,c,0,0,0)

__device__ __forceinline__ u32 pack_bf2(float lo, float hi) {
    __hip_bfloat162 h = __float22bfloat162_rn(make_float2(lo, hi));
    u32 r; __builtin_memcpy(&r, &h, 4); return r;
}
__device__ __forceinline__ short f2bfs(float v) {
    __hip_bfloat16 h = __float2bfloat16(v);
    short r; __builtin_memcpy(&r, &h, 2); return r;
}
__device__ __forceinline__ float bf2f(short s) {
    u32 u = ((u32)(unsigned short)s) << 16;
    float f; __builtin_memcpy(&f, &u, 4); return f;
}
// tanh-form GELU: max abs err ~3e-4 vs exact erf form (well under tolerance)
__device__ __forceinline__ float gelu_t(float x) {
    float x2 = x * x;
    float t = x * fmaf(0.10294828f, x2, 2.30220913f);  // 2u*log2(e)
    float e = exp2f(t);
    float r = __builtin_amdgcn_rcpf(e + 1.0f);
    return fmaf(-x, r, x);                              // x * (1 - 1/(e+1))
}

union frag { bf16x8 v; u32 w[4]; };

// ---------------------------------------------------------------------------
// Kernel W: pre-transform W1/W2 into MFMA frag-layout bf16 tables (one-time)
// slot for elem (k,feat): ((mt*8+ks)*64 + h2*32 + (feat&31))*8 + j
// ---------------------------------------------------------------------------
__global__ __launch_bounds__(256) void prep_weights_kernel(
    const float* __restrict__ W1, const float* __restrict__ W2,
    short* __restrict__ Wt1, short* __restrict__ Wt2)
{
    int e = blockIdx.x * 256 + threadIdx.x;   // 0..16383
    if (e >= HH * HH) return;
    int feat = e & 127, k = e >> 7;
    int mt = feat >> 5, ks = k >> 4, h2 = (k >> 3) & 1, j = k & 7;
    int slot = ((mt * 8 + ks) * 64 + h2 * 32 + (feat & 31)) * 8 + j;
    Wt1[slot] = f2bfs(W1[e]);
    Wt2[slot] = f2bfs(W2[e]);
}

// ---------------------------------------------------------------------------
// Kernel A: Ysrc = bf16((enc*mask) @ W0[0:128]), Yself = bf16(.. @ W0[128:256] + b0)
// ---------------------------------------------------------------------------
__global__ __launch_bounds__(128) void precompute_kernel(
    const float* __restrict__ enc, const float* __restrict__ mask,
    const float* __restrict__ W0, const float* __restrict__ b0,
    __hip_bfloat16* __restrict__ Ysrc, __hip_bfloat16* __restrict__ Yself)
{
    const int tid = threadIdx.x;
    const int wave = tid >> 6;
    const int lane = tid & 63;
    const int li = lane & 31;
    const int hi = lane >> 5;
    const int rowBase = blockIdx.x * 64 + wave * 32;
    const int myrow = rowBase + li;

    const float m = mask[myrow];
    bf16x8 A[8];
    #pragma unroll
    for (int ks = 0; ks < 8; ++ks) {
        const float* p = enc + (size_t)myrow * HH + ks * 16 + hi * 8;
        float4 a = *(const float4*)p;
        float4 c = *(const float4*)(p + 4);
        frag f;
        f.w[0] = pack_bf2(a.x * m, a.y * m);
        f.w[1] = pack_bf2(a.z * m, a.w * m);
        f.w[2] = pack_bf2(c.x * m, c.y * m);
        f.w[3] = pack_bf2(c.z * m, c.w * m);
        A[ks] = f.v;
    }

    #pragma unroll
    for (int h2 = 0; h2 < 2; ++h2) {
        __hip_bfloat16* dest = h2 ? Yself : Ysrc;
        #pragma unroll 1
        for (int mt = 0; mt < 4; ++mt) {
            const float bias = h2 ? b0[mt * 32 + li] : 0.0f;
            f32x16 acc;
            #pragma unroll
            for (int r = 0; r < 16; ++r) acc[r] = 0.f;
            #pragma unroll
            for (int ks = 0; ks < 8; ++ks) {
                bf16x8 Bf;
                #pragma unroll
                for (int j = 0; j < 8; ++j) {
                    int k = ks * 16 + hi * 8 + j;
                    Bf[j] = f2bfs(W0[(size_t)(h2 * HH + k) * HH + mt * 32 + li]);
                }
                acc = MFMA(A[ks], Bf, acc);
            }
            #pragma unroll
            for (int r = 0; r < 16; ++r) {
                int rrow = (r & 3) + 8 * (r >> 2) + 4 * hi;
                dest[(size_t)(rowBase + rrow) * HH + mt * 32 + li] =
                    __float2bfloat16(acc[r] + bias);
            }
        }
    }
}

// ---------------------------------------------------------------------------
// Kernel B: per-edge MLP + masked mean. r8's no-spill structure (H0 in LDS,
// one acc tile at a time) with weight frags read from global (L1/L2-hot).
// ---------------------------------------------------------------------------
__global__ __launch_bounds__(THREADS) void mpnn_kernel(
    const float* __restrict__ enc, const float* __restrict__ mask,
    const float* __restrict__ dist, const int* __restrict__ eidx,
    const __hip_bfloat16* __restrict__ Ysrc, const __hip_bfloat16* __restrict__ Yself,
    const float* __restrict__ W0,
    const short* __restrict__ Wt1, const float* __restrict__ b1,
    const short* __restrict__ Wt2, const float* __restrict__ b2,
    float* __restrict__ upd)
{
    extern __shared__ char lds[];
    const int tid  = threadIdx.x;
    const int wave = tid >> 6;
    const int lane = tid & 63;
    const int li   = lane & 31;
    const int hi   = lane >> 5;
    const int nodeBase = blockIdx.x * NPB;

    {
        uint4* sv = (uint4*)(lds + OFF_SELF);
        sv[tid] = *(const uint4*)(Yself + (size_t)nodeBase * HH + tid * 8);
    }
    short* swd = (short*)(lds + OFF_WD);
    if (tid < HH) swd[tid] = f2bfs(W0[(size_t)256 * HH + tid]);
    float* s_b1f = (float*)(lds + OFF_B1);
    if (tid < HH) s_b1f[tid] = b1[tid];
    float* s_b2f = (float*)(lds + OFF_B2);
    if (tid < HH) s_b2f[tid] = b2[tid];
    __syncthreads();

    const int b = nodeBase >> 12;
    const __hip_bfloat16* YsB = Ysrc + (size_t)b * NN * HH;
    // per-wave H0 staging buffer: [ks][lane] x 16 B
    char* h0buf = lds + OFF_H0 + (size_t)wave * 8 * 64 * 16;

    #pragma unroll 1
    for (int i = 0; i < NPI; ++i) {
        const int node_local = wave * NPI + i;
        const int gnode = nodeBase + node_local;

        int ie = eidx[(size_t)gnode * KK + li];
        float dste = dist[(size_t)gnode * KK + li];
        float mask_n = mask[gnode];
        bool valid = ie >= 0;
        int ic = valid ? ie : 0;
        u32 vmask = (u32)__ballot(valid);
        int vc = __popc(vmask);
        float inv_vc = 1.0f / (float)(vc < 1 ? 1 : vc);

        // ---- layer 0: gather + elementwise add/gelu -> H0 to LDS ----
        const char* gbase = (const char*)(YsB + (size_t)ic * HH) + hi * 16;
        const short* sself = (const short*)(lds + OFF_SELF) + node_local * HH;
        {
            bf16x8 g[8];
            #pragma unroll
            for (int ks = 0; ks < 8; ++ks) g[ks] = *(const bf16x8*)(gbase + ks * 32);
            #pragma unroll
            for (int ks = 0; ks < 8; ++ks) {
                bf16x8 ys = *(const bf16x8*)(sself + ks * 16 + hi * 8);
                bf16x8 wd = *(const bf16x8*)(swd + ks * 16 + hi * 8);
                frag h;
                #pragma unroll
                for (int q = 0; q < 4; ++q) {
                    float f0 = gelu_t(bf2f(g[ks][2*q])   + bf2f(ys[2*q])   + dste * bf2f(wd[2*q]));
                    float f1 = gelu_t(bf2f(g[ks][2*q+1]) + bf2f(ys[2*q+1]) + dste * bf2f(wd[2*q+1]));
                    h.w[q] = pack_bf2(f0, f1);
                }
                *(bf16x8*)(h0buf + (ks * 64 + lane) * 16) = h.v;
            }
        }

        // ---- layer 1 (transposed): A from global Wt1, B re-read from LDS ----
        frag F2[8];
        #pragma unroll
        for (int mt = 0; mt < 4; ++mt) {
            f32x16 acc;
            #pragma unroll
            for (int r = 0; r < 16; ++r) acc[r] = 0.f;
            #pragma unroll
            for (int ks = 0; ks < 8; ++ks) {
                bf16x8 a = *(const bf16x8*)(Wt1 + ((size_t)(mt * 8 + ks) * 64 + lane) * 8);
                bf16x8 h0 = *(const bf16x8*)(h0buf + (ks * 64 + lane) * 16);
                acc = MFMA(a, h0, acc);
            }
            u32 pk8[8];
            #pragma unroll
            for (int q = 0; q < 8; ++q) {
                int row0 = 8 * (q >> 1) + 2 * (q & 1) + 4 * hi;   // rows row0,row0+1
                float2 bb = *(const float2*)(s_b1f + mt * 32 + row0);
                pk8[q] = pack_bf2(gelu_t(acc[2*q] + bb.x), gelu_t(acc[2*q+1] + bb.y));
            }
            #pragma unroll
            for (int e = 0; e < 2; ++e) {
                const int ks = 2 * mt + e;
                #pragma unroll
                for (int r = 0; r < 4; ++r) {
                    const int q0 = (r & 1) + 4 * e;
                    u32 own  = hi ? pk8[q0 + 2] : pk8[q0];
                    u32 give = hi ? pk8[q0]     : pk8[q0 + 2];
                    u32 got  = (u32)__shfl_xor((int)give, 32, 64);
                    F2[ks].w[r] = ((r >> 1) == hi) ? own : got;
                }
            }
        }

        // ---- layer 2 (normal), B from global Wt2, one nt-tile at a time ----
        float s0, s1, s2, s3;
        #pragma unroll
        for (int nt = 0; nt < 4; ++nt) {
            f32x16 acc;
            #pragma unroll
            for (int r = 0; r < 16; ++r) acc[r] = 0.f;
            #pragma unroll
            for (int ks = 0; ks < 8; ++ks) {
                bf16x8 w2f = *(const bf16x8*)(Wt2 + ((size_t)(nt * 8 + ks) * 64 + lane) * 8);
                acc = MFMA(F2[ks].v, w2f, acc);
            }
            float bv = s_b2f[nt * 32 + li];
            float t = 0.f;
            #pragma unroll
            for (int r = 0; r < 16; ++r) {
                float v = gelu_t(acc[r] + bv);
                int edge = (r & 3) + 8 * (r >> 2) + 4 * hi;
                t += ((vmask >> edge) & 1) ? v : 0.f;
            }
            t += __shfl_xor(t, 32, 64);
            if (nt == 0) s0 = t; else if (nt == 1) s1 = t;
            else if (nt == 2) s2 = t; else s3 = t;
        }

        // ---- epilogue: thread writes feats (hi*2)*32+li and (hi*2+1)*32+li ----
        float sa = hi ? s2 : s0;
        float sb = hi ? s3 : s1;
        int f0 = (hi * 2) * 32 + li;
        int f1 = (hi * 2 + 1) * 32 + li;
        float u0 = (enc[(size_t)gnode * HH + f0] + sa * inv_vc) * mask_n;
        float u1 = (enc[(size_t)gnode * HH + f1] + sb * inv_vc) * mask_n;
        upd[(size_t)gnode * HH + f0] = u0;
        upd[(size_t)gnode * HH + f1] = u1;
    }
}

// ---------------------------------------------------------------------------
// Kernel 2a: partial sums/sumsq over 128-row chunks -> (B,32,H)
// ---------------------------------------------------------------------------
#define RCHUNK 128
__global__ __launch_bounds__(128) void reduce_partial_kernel(
    const float* __restrict__ upd, float* __restrict__ psum, float* __restrict__ psumsq)
{
    const int blk = blockIdx.x;
    const int b = blk >> 5;
    const int p = blk & 31;
    const int j = threadIdx.x;
    const size_t base = ((size_t)b * NN + (size_t)p * RCHUNK) * HH + j;
    float s = 0.f, s2 = 0.f;
    #pragma unroll 4
    for (int r = 0; r < RCHUNK; ++r) {
        float v = upd[base + (size_t)r * HH];
        s += v;
        s2 = fmaf(v, v, s2);
    }
    psum[(size_t)blk * HH + j]   = s;
    psumsq[(size_t)blk * HH + j] = s2;
}

// ---------------------------------------------------------------------------
// Kernel 2b: combine partials -> mean, 1/std per (b, feature)
// ---------------------------------------------------------------------------
__global__ __launch_bounds__(128) void finalize_stats_kernel(
    const float* __restrict__ psum, const float* __restrict__ psumsq,
    const float* __restrict__ mask, float* __restrict__ meanp, float* __restrict__ istdp)
{
    const int b = blockIdx.x;
    const int j = threadIdx.x;
    float s = 0.f, s2 = 0.f;
    #pragma unroll 4
    for (int c = 0; c < 32; ++c) {
        s  += psum[((size_t)b * 32 + c) * HH + j];
        s2 += psumsq[((size_t)b * 32 + c) * HH + j];
    }
    float cpart = 0.f;
    #pragma unroll 4
    for (int t = 0; t < NN / HH; ++t)
        cpart += mask[(size_t)b * NN + (size_t)t * HH + j];
    __shared__ float red[HH];
    red[j] = cpart;
    __syncthreads();
    for (int off = HH / 2; off > 0; off >>= 1) {
        if (j < off) red[j] += red[j + off];
        __syncthreads();
    }
    float counts = red[0];
    if (counts == 0.f) counts = 1.f;
    float mean = s / counts;
    float var  = (s2 - 2.f * mean * s + (float)NN * mean * mean) / counts;
    meanp[b * HH + j] = mean;
    istdp[b * HH + j] = 1.0f / sqrtf(var + 1e-5f);
}

// ---------------------------------------------------------------------------
// Kernel 3: normalize out0 in place + write pass-through outputs
// ---------------------------------------------------------------------------
__global__ void write_out_kernel(
    const float* __restrict__ mask, const float* __restrict__ dist,
    const int* __restrict__ eidx, const float* __restrict__ meanp,
    const float* __restrict__ istdp, const float* __restrict__ scale,
    const float* __restrict__ shift, float* __restrict__ out)
{
    const size_t T0 = (size_t)BB * NN * HH;
    const size_t T1 = (size_t)BB * NN;
    const size_t T2 = (size_t)BB * NN * KK;
    const size_t stride = (size_t)gridDim.x * blockDim.x;
    const size_t t = (size_t)blockIdx.x * blockDim.x + threadIdx.x;

    for (size_t x = t; x < T0; x += stride) {
        int h = (int)(x & (HH - 1));
        size_t bn = x >> 7;
        int b = (int)(bn >> 12);
        float m = mask[bn];
        float v = (out[x] - meanp[b * HH + h]) * istdp[b * HH + h] * scale[h] + shift[h];
        out[x] = v * m;
    }
    float* out1 = out + T0;
    for (size_t x = t; x < T1; x += stride) out1[x] = mask[x];
    float* out2 = out1 + T1;
    for (size_t x = t; x < T2; x += stride) out2[x] = dist[x];
    float* out3 = out2 + T2;
    for (size_t x = t; x < T2; x += stride) out3[x] = (float)eidx[x];
}

// ---------------------------------------------------------------------------
extern "C" void kernel_launch(void* const* d_in, const int* in_sizes, int n_in,
                              void* d_out, int out_size, void* d_ws, size_t ws_size,
                              hipStream_t stream) {
    const float* enc   = (const float*)d_in[0];
    const float* mask  = (const float*)d_in[1];
    const float* dist  = (const float*)d_in[2];
    const int*   eidx  = (const int*)  d_in[3];
    const float* W0    = (const float*)d_in[4];
    const float* b0    = (const float*)d_in[5];
    const float* W1    = (const float*)d_in[6];
    const float* b1    = (const float*)d_in[7];
    const float* W2    = (const float*)d_in[8];
    const float* b2    = (const float*)d_in[9];
    const float* scale = (const float*)d_in[10];
    const float* shift = (const float*)d_in[11];
    float* out = (float*)d_out;
    float* upd = out;   // pre-norm upd lives in out[0:B*N*H], normalized in place later

    const size_t T0 = (size_t)BB * NN * HH;
    const size_t T1 = (size_t)BB * NN;

    __hip_bfloat16* Ysrc  = (__hip_bfloat16*)d_ws;                 // 4 MB
    __hip_bfloat16* Yself = (__hip_bfloat16*)(out + T0 + T1);      // 4 MB (out2/out3 region, overwritten last)
    float* wsf    = (float*)((char*)d_ws + (size_t)BB * NN * HH * 2);
    float* psum   = wsf;                                           // 64 KB
    float* psumsq = psum + (size_t)BB * 32 * HH;                   // 64 KB
    float* meanp  = psumsq + (size_t)BB * 32 * HH;
    float* istdp  = meanp + (size_t)BB * HH;
    short* Wt1    = (short*)((char*)d_ws + (size_t)BB * NN * HH * 2 + 262144);
    short* Wt2    = Wt1 + HH * HH;

    hipFuncSetAttribute((const void*)mpnn_kernel,
                        hipFuncAttributeMaxDynamicSharedMemorySize, LDS_TOTAL);

    prep_weights_kernel<<<dim3(64), dim3(256), 0, stream>>>(W1, W2, Wt1, Wt2);
    precompute_kernel<<<dim3(256), dim3(128), 0, stream>>>(enc, mask, W0, b0, Ysrc, Yself);
    mpnn_kernel<<<dim3((BB * NN) / NPB), dim3(THREADS), LDS_TOTAL, stream>>>(
        enc, mask, dist, eidx, Ysrc, Yself, W0, Wt1, b1, Wt2, b2, upd);
    reduce_partial_kernel<<<dim3(BB * 32), dim3(128), 0, stream>>>(upd, psum, psumsq);
    finalize_stats_kernel<<<dim3(BB), dim3(128), 0, stream>>>(psum, psumsq, mask, meanp, istdp);
    write_out_kernel<<<dim3(1024), dim3(256), 0, stream>>>(
        mask, dist, eidx, meanp, istdp, scale, shift, out);
}

// Round 13
// 171.650 us; speedup vs baseline: 1.6336x; 1.6336x over previous
//
#include <hip/hip_runtime.h>
#include <hip/hip_bf16.h>
#include <math.h>

#define BB 4
#define NN 4096
#define KK 32
#define HH 128

#define NPB 32        // nodes per block
#define THREADS 512   // 8 waves, 4 nodes per wave
#define NPI (NPB / 8) // nodes per wave

typedef short bf16x8 __attribute__((ext_vector_type(8)));
typedef float f32x16 __attribute__((ext_vector_type(16)));
typedef unsigned int u32;

// LDS map (137.25 KB -> 1 block/CU). r8's proven no-spill structure:
// H0 staged in per-wave LDS, W1/W2 frag tables in LDS, one acc tile at a
// time. r9/r10/r11 (H0 in regs) and r12 (weights in global) all spilled.
#define OFF_W1   0
#define OFF_W2   32768
#define OFF_H0   65536                     // 8 waves x 8 ks x 64 lanes x 16 B = 65536 B
#define OFF_SELF (OFF_H0 + 65536)          // 32 nodes x 128 bf16 = 8192 B
#define OFF_WD   (OFF_SELF + NPB*HH*2)     // 256 B
#define OFF_B1   (OFF_WD + HH*2)           // 512 B (f32 b1)
#define OFF_B2   (OFF_B1 + HH*4)           // 512 B (f32 b2)
#define LDS_TOTAL (OFF_B2 + HH*4)          // 140544 B

#define MFMA(a,b,c) __builtin_amdgcn_mfma_f32_32x32x16_bf16(a,b,c,0,0,0)

__device__ __forceinline__ u32 pack_bf2(float lo, float hi) {
    __hip_bfloat162 h = __float22bfloat162_rn(make_float2(lo, hi));
    u32 r; __builtin_memcpy(&r, &h, 4); return r;
}
__device__ __forceinline__ short f2bfs(float v) {
    __hip_bfloat16 h = __float2bfloat16(v);
    short r; __builtin_memcpy(&r, &h, 2); return r;
}
__device__ __forceinline__ float bf2f(short s) {
    u32 u = ((u32)(unsigned short)s) << 16;
    float f; __builtin_memcpy(&f, &u, 4); return f;
}
// tanh-form GELU: max abs err ~3e-4 vs exact erf form (well under tolerance)
__device__ __forceinline__ float gelu_t(float x) {
    float x2 = x * x;
    float t = x * fmaf(0.10294828f, x2, 2.30220913f);  // 2u*log2(e)
    float e = exp2f(t);
    float r = __builtin_amdgcn_rcpf(e + 1.0f);
    return fmaf(-x, r, x);                              // x * (1 - 1/(e+1))
}

union frag { bf16x8 v; u32 w[4]; };

// ---------------------------------------------------------------------------
// Kernel A: Ysrc = bf16((enc*mask) @ W0[0:128]), Yself = bf16(.. @ W0[128:256] + b0)
// ---------------------------------------------------------------------------
__global__ __launch_bounds__(128) void precompute_kernel(
    const float* __restrict__ enc, const float* __restrict__ mask,
    const float* __restrict__ W0, const float* __restrict__ b0,
    __hip_bfloat16* __restrict__ Ysrc, __hip_bfloat16* __restrict__ Yself)
{
    const int tid = threadIdx.x;
    const int wave = tid >> 6;
    const int lane = tid & 63;
    const int li = lane & 31;
    const int hi = lane >> 5;
    const int rowBase = blockIdx.x * 64 + wave * 32;
    const int myrow = rowBase + li;

    const float m = mask[myrow];
    bf16x8 A[8];
    #pragma unroll
    for (int ks = 0; ks < 8; ++ks) {
        const float* p = enc + (size_t)myrow * HH + ks * 16 + hi * 8;
        float4 a = *(const float4*)p;
        float4 c = *(const float4*)(p + 4);
        frag f;
        f.w[0] = pack_bf2(a.x * m, a.y * m);
        f.w[1] = pack_bf2(a.z * m, a.w * m);
        f.w[2] = pack_bf2(c.x * m, c.y * m);
        f.w[3] = pack_bf2(c.z * m, c.w * m);
        A[ks] = f.v;
    }

    #pragma unroll
    for (int h2 = 0; h2 < 2; ++h2) {
        __hip_bfloat16* dest = h2 ? Yself : Ysrc;
        #pragma unroll 1
        for (int mt = 0; mt < 4; ++mt) {
            const float bias = h2 ? b0[mt * 32 + li] : 0.0f;
            f32x16 acc;
            #pragma unroll
            for (int r = 0; r < 16; ++r) acc[r] = 0.f;
            #pragma unroll
            for (int ks = 0; ks < 8; ++ks) {
                bf16x8 Bf;
                #pragma unroll
                for (int j = 0; j < 8; ++j) {
                    int k = ks * 16 + hi * 8 + j;
                    Bf[j] = f2bfs(W0[(size_t)(h2 * HH + k) * HH + mt * 32 + li]);
                }
                acc = MFMA(A[ks], Bf, acc);
            }
            #pragma unroll
            for (int r = 0; r < 16; ++r) {
                int rrow = (r & 3) + 8 * (r >> 2) + 4 * hi;
                dest[(size_t)(rowBase + rrow) * HH + mt * 32 + li] =
                    __float2bfloat16(acc[r] + bias);
            }
        }
    }
}

// ---------------------------------------------------------------------------
// Kernel B: r8's no-spill structure + register prefetch of next node's gather
// (issued after H0-store where the gather regs are dead; hides ~900cyc L2/L3
// latency under layer-1/2 compute). Peak live ~115 VGPR.
// ---------------------------------------------------------------------------
__global__ __launch_bounds__(THREADS) void mpnn_kernel(
    const float* __restrict__ enc, const float* __restrict__ mask,
    const float* __restrict__ dist, const int* __restrict__ eidx,
    const __hip_bfloat16* __restrict__ Ysrc, const __hip_bfloat16* __restrict__ Yself,
    const float* __restrict__ W0,
    const float* __restrict__ W1, const float* __restrict__ b1,
    const float* __restrict__ W2, const float* __restrict__ b2,
    float* __restrict__ upd)
{
    extern __shared__ char lds[];
    const int tid  = threadIdx.x;
    const int wave = tid >> 6;
    const int lane = tid & 63;
    const int li   = lane & 31;
    const int hi   = lane >> 5;
    const int nodeBase = blockIdx.x * NPB;

    // ---- stage W1/W2 fragment tables (bf16, MFMA frag layout) ----
    #pragma unroll
    for (int tbl = 0; tbl < 2; ++tbl) {
        const float* W = tbl ? W2 : W1;
        short* dst = (short*)(lds + tbl * 32768);
        #pragma unroll
        for (int i = 0; i < (HH * HH) / THREADS; ++i) {
            int e = i * THREADS + tid;
            int feat = e & 127, k = e >> 7;
            float v = W[(size_t)k * HH + feat];
            int mt = feat >> 5, ks = k >> 4, h2 = (k >> 3) & 1, j = k & 7;
            dst[((mt * 8 + ks) * 64 + h2 * 32 + (feat & 31)) * 8 + j] = f2bfs(v);
        }
    }
    {
        uint4* sv = (uint4*)(lds + OFF_SELF);
        sv[tid] = *(const uint4*)(Yself + (size_t)nodeBase * HH + tid * 8);
    }
    short* swd = (short*)(lds + OFF_WD);
    if (tid < HH) swd[tid] = f2bfs(W0[(size_t)256 * HH + tid]);
    float* s_b1f = (float*)(lds + OFF_B1);
    if (tid < HH) s_b1f[tid] = b1[tid];
    float* s_b2f = (float*)(lds + OFF_B2);
    if (tid < HH) s_b2f[tid] = b2[tid];
    __syncthreads();

    const int b = nodeBase >> 12;
    const __hip_bfloat16* YsB = Ysrc + (size_t)b * NN * HH;
    // per-wave H0 staging buffer: [ks][lane] x 16 B
    char* h0buf = lds + OFF_H0 + (size_t)wave * 8 * 64 * 16;

    // ---- prologue: gather + meta for first node ----
    const int node0 = wave * NPI;
    int   ie = eidx[(size_t)(nodeBase + node0) * KK + li];
    float dd = dist[(size_t)(nodeBase + node0) * KK + li];
    float mk = mask[nodeBase + node0];
    bf16x8 g[8];
    {
        int ic0 = ie < 0 ? 0 : ie;
        const char* gb = (const char*)(YsB + (size_t)ic0 * HH) + hi * 16;
        #pragma unroll
        for (int ks = 0; ks < 8; ++ks) g[ks] = *(const bf16x8*)(gb + ks * 32);
    }

    #pragma unroll 1
    for (int i = 0; i < NPI; ++i) {
        const int node_local = node0 + i;
        const int gnode = nodeBase + node_local;

        // snapshot current node's scalars before prefetch overwrites them
        bool valid = ie >= 0;
        u32 vmask = (u32)__ballot(valid);
        int vc = __popc(vmask);
        float inv_vc = 1.0f / (float)(vc < 1 ? 1 : vc);
        float dste = dd;
        float mask_n = mk;

        // ---- layer 0: elementwise add/gelu -> H0 to LDS (g dies here) ----
        const short* sself = (const short*)(lds + OFF_SELF) + node_local * HH;
        #pragma unroll
        for (int ks = 0; ks < 8; ++ks) {
            bf16x8 ys = *(const bf16x8*)(sself + ks * 16 + hi * 8);
            bf16x8 wd = *(const bf16x8*)(swd + ks * 16 + hi * 8);
            frag h;
            #pragma unroll
            for (int q = 0; q < 4; ++q) {
                float f0 = gelu_t(bf2f(g[ks][2*q])   + bf2f(ys[2*q])   + dste * bf2f(wd[2*q]));
                float f1 = gelu_t(bf2f(g[ks][2*q+1]) + bf2f(ys[2*q+1]) + dste * bf2f(wd[2*q+1]));
                h.w[q] = pack_bf2(f0, f1);
            }
            *(bf16x8*)(h0buf + (ks * 64 + lane) * 16) = h.v;
        }

        // ---- prefetch next node's gather + meta (hides under layers 1-2) ----
        if (i + 1 < NPI) {
            ie = eidx[(size_t)(gnode + 1) * KK + li];
            dd = dist[(size_t)(gnode + 1) * KK + li];
            mk = mask[gnode + 1];
            int icn = ie < 0 ? 0 : ie;
            const char* gb = (const char*)(YsB + (size_t)icn * HH) + hi * 16;
            #pragma unroll
            for (int ks = 0; ks < 8; ++ks) g[ks] = *(const bf16x8*)(gb + ks * 32);
        }

        // ---- layer 1 (transposed): per mt-tile, B re-read from LDS ----
        frag F2[8];
        #pragma unroll
        for (int mt = 0; mt < 4; ++mt) {
            f32x16 acc;
            #pragma unroll
            for (int r = 0; r < 16; ++r) acc[r] = 0.f;
            #pragma unroll
            for (int ks = 0; ks < 8; ++ks) {
                bf16x8 a = *(const bf16x8*)(lds + OFF_W1 + ((mt * 8 + ks) * 64 + lane) * 16);
                bf16x8 h0 = *(const bf16x8*)(h0buf + (ks * 64 + lane) * 16);
                acc = MFMA(a, h0, acc);
            }
            u32 pk8[8];
            #pragma unroll
            for (int q = 0; q < 8; ++q) {
                int row0 = 8 * (q >> 1) + 2 * (q & 1) + 4 * hi;   // rows row0,row0+1
                float2 bb = *(const float2*)(s_b1f + mt * 32 + row0);
                pk8[q] = pack_bf2(gelu_t(acc[2*q] + bb.x), gelu_t(acc[2*q+1] + bb.y));
            }
            #pragma unroll
            for (int e = 0; e < 2; ++e) {
                const int ks = 2 * mt + e;
                #pragma unroll
                for (int r = 0; r < 4; ++r) {
                    const int q0 = (r & 1) + 4 * e;
                    u32 own  = hi ? pk8[q0 + 2] : pk8[q0];
                    u32 give = hi ? pk8[q0]     : pk8[q0 + 2];
                    u32 got  = (u32)__shfl_xor((int)give, 32, 64);
                    F2[ks].w[r] = ((r >> 1) == hi) ? own : got;
                }
            }
        }

        // ---- layer 2 (normal), one nt-tile at a time -> scalars ----
        float s0, s1, s2, s3;
        #pragma unroll
        for (int nt = 0; nt < 4; ++nt) {
            f32x16 acc;
            #pragma unroll
            for (int r = 0; r < 16; ++r) acc[r] = 0.f;
            #pragma unroll
            for (int ks = 0; ks < 8; ++ks) {
                bf16x8 w2f = *(const bf16x8*)(lds + OFF_W2 + ((nt * 8 + ks) * 64 + lane) * 16);
                acc = MFMA(F2[ks].v, w2f, acc);
            }
            float bv = s_b2f[nt * 32 + li];
            float t = 0.f;
            #pragma unroll
            for (int r = 0; r < 16; ++r) {
                float v = gelu_t(acc[r] + bv);
                int edge = (r & 3) + 8 * (r >> 2) + 4 * hi;
                t += ((vmask >> edge) & 1) ? v : 0.f;
            }
            t += __shfl_xor(t, 32, 64);
            if (nt == 0) s0 = t; else if (nt == 1) s1 = t;
            else if (nt == 2) s2 = t; else s3 = t;
        }

        // ---- epilogue: thread writes feats (hi*2)*32+li and (hi*2+1)*32+li ----
        float sa = hi ? s2 : s0;
        float sb = hi ? s3 : s1;
        int f0 = (hi * 2) * 32 + li;
        int f1 = (hi * 2 + 1) * 32 + li;
        float u0 = (enc[(size_t)gnode * HH + f0] + sa * inv_vc) * mask_n;
        float u1 = (enc[(size_t)gnode * HH + f1] + sb * inv_vc) * mask_n;
        upd[(size_t)gnode * HH + f0] = u0;
        upd[(size_t)gnode * HH + f1] = u1;
    }
}

// ---------------------------------------------------------------------------
// Kernel 2a: partial sums/sumsq over 128-row chunks -> (B,32,H)
// ---------------------------------------------------------------------------
#define RCHUNK 128
__global__ __launch_bounds__(128) void reduce_partial_kernel(
    const float* __restrict__ upd, float* __restrict__ psum, float* __restrict__ psumsq)
{
    const int blk = blockIdx.x;
    const int b = blk >> 5;
    const int p = blk & 31;
    const int j = threadIdx.x;
    const size_t base = ((size_t)b * NN + (size_t)p * RCHUNK) * HH + j;
    float s = 0.f, s2 = 0.f;
    #pragma unroll 4
    for (int r = 0; r < RCHUNK; ++r) {
        float v = upd[base + (size_t)r * HH];
        s += v;
        s2 = fmaf(v, v, s2);
    }
    psum[(size_t)blk * HH + j]   = s;
    psumsq[(size_t)blk * HH + j] = s2;
}

// ---------------------------------------------------------------------------
// Kernel 2b: combine partials -> mean, 1/std per (b, feature)
// ---------------------------------------------------------------------------
__global__ __launch_bounds__(128) void finalize_stats_kernel(
    const float* __restrict__ psum, const float* __restrict__ psumsq,
    const float* __restrict__ mask, float* __restrict__ meanp, float* __restrict__ istdp)
{
    const int b = blockIdx.x;
    const int j = threadIdx.x;
    float s = 0.f, s2 = 0.f;
    #pragma unroll 4
    for (int c = 0; c < 32; ++c) {
        s  += psum[((size_t)b * 32 + c) * HH + j];
        s2 += psumsq[((size_t)b * 32 + c) * HH + j];
    }
    float cpart = 0.f;
    #pragma unroll 4
    for (int t = 0; t < NN / HH; ++t)
        cpart += mask[(size_t)b * NN + (size_t)t * HH + j];
    __shared__ float red[HH];
    red[j] = cpart;
    __syncthreads();
    for (int off = HH / 2; off > 0; off >>= 1) {
        if (j < off) red[j] += red[j + off];
        __syncthreads();
    }
    float counts = red[0];
    if (counts == 0.f) counts = 1.f;
    float mean = s / counts;
    float var  = (s2 - 2.f * mean * s + (float)NN * mean * mean) / counts;
    meanp[b * HH + j] = mean;
    istdp[b * HH + j] = 1.0f / sqrtf(var + 1e-5f);
}

// ---------------------------------------------------------------------------
// Kernel 3: normalize out0 in place + write pass-through outputs
// ---------------------------------------------------------------------------
__global__ void write_out_kernel(
    const float* __restrict__ mask, const float* __restrict__ dist,
    const int* __restrict__ eidx, const float* __restrict__ meanp,
    const float* __restrict__ istdp, const float* __restrict__ scale,
    const float* __restrict__ shift, float* __restrict__ out)
{
    const size_t T0 = (size_t)BB * NN * HH;
    const size_t T1 = (size_t)BB * NN;
    const size_t T2 = (size_t)BB * NN * KK;
    const size_t stride = (size_t)gridDim.x * blockDim.x;
    const size_t t = (size_t)blockIdx.x * blockDim.x + threadIdx.x;

    for (size_t x = t; x < T0; x += stride) {
        int h = (int)(x & (HH - 1));
        size_t bn = x >> 7;
        int b = (int)(bn >> 12);
        float m = mask[bn];
        float v = (out[x] - meanp[b * HH + h]) * istdp[b * HH + h] * scale[h] + shift[h];
        out[x] = v * m;
    }
    float* out1 = out + T0;
    for (size_t x = t; x < T1; x += stride) out1[x] = mask[x];
    float* out2 = out1 + T1;
    for (size_t x = t; x < T2; x += stride) out2[x] = dist[x];
    float* out3 = out2 + T2;
    for (size_t x = t; x < T2; x += stride) out3[x] = (float)eidx[x];
}

// ---------------------------------------------------------------------------
extern "C" void kernel_launch(void* const* d_in, const int* in_sizes, int n_in,
                              void* d_out, int out_size, void* d_ws, size_t ws_size,
                              hipStream_t stream) {
    const float* enc   = (const float*)d_in[0];
    const float* mask  = (const float*)d_in[1];
    const float* dist  = (const float*)d_in[2];
    const int*   eidx  = (const int*)  d_in[3];
    const float* W0    = (const float*)d_in[4];
    const float* b0    = (const float*)d_in[5];
    const float* W1    = (const float*)d_in[6];
    const float* b1    = (const float*)d_in[7];
    const float* W2    = (const float*)d_in[8];
    const float* b2    = (const float*)d_in[9];
    const float* scale = (const float*)d_in[10];
    const float* shift = (const float*)d_in[11];
    float* out = (float*)d_out;
    float* upd = out;   // pre-norm upd lives in out[0:B*N*H], normalized in place later

    const size_t T0 = (size_t)BB * NN * HH;
    const size_t T1 = (size_t)BB * NN;

    __hip_bfloat16* Ysrc  = (__hip_bfloat16*)d_ws;                 // 4 MB
    __hip_bfloat16* Yself = (__hip_bfloat16*)(out + T0 + T1);      // 4 MB (out2/out3 region, overwritten last)
    float* wsf    = (float*)((char*)d_ws + (size_t)BB * NN * HH * 2);
    float* psum   = wsf;
    float* psumsq = psum + (size_t)BB * 32 * HH;
    float* meanp  = psumsq + (size_t)BB * 32 * HH;
    float* istdp  = meanp + (size_t)BB * HH;

    hipFuncSetAttribute((const void*)mpnn_kernel,
                        hipFuncAttributeMaxDynamicSharedMemorySize, LDS_TOTAL);

    precompute_kernel<<<dim3(256), dim3(128), 0, stream>>>(enc, mask, W0, b0, Ysrc, Yself);
    mpnn_kernel<<<dim3((BB * NN) / NPB), dim3(THREADS), LDS_TOTAL, stream>>>(
        enc, mask, dist, eidx, Ysrc, Yself, W0, W1, b1, W2, b2, upd);
    reduce_partial_kernel<<<dim3(BB * 32), dim3(128), 0, stream>>>(upd, psum, psumsq);
    finalize_stats_kernel<<<dim3(BB), dim3(128), 0, stream>>>(psum, psumsq, mask, meanp, istdp);
    write_out_kernel<<<dim3(1024), dim3(256), 0, stream>>>(
        mask, dist, eidx, meanp, istdp, scale, shift, out);
}

// Round 14
// 164.576 us; speedup vs baseline: 1.7039x; 1.0430x over previous
//
#include <hip/hip_runtime.h>
#include <hip/hip_bf16.h>
#include <math.h>

#define BB 4
#define NN 4096
#define KK 32
#define HH 128

#define NPB 64        // nodes per block -> grid 256 = exactly 1 block/CU
#define THREADS 512   // 8 waves, 8 nodes per wave
#define NPI (NPB / 8) // nodes per wave
#define NBLK ((BB * NN) / NPB)       // 256 blocks
#define BPB (NBLK / BB)              // 64 blocks per batch

typedef short bf16x8 __attribute__((ext_vector_type(8)));
typedef float f32x16 __attribute__((ext_vector_type(16)));
typedef unsigned int u32;

// LDS map (145.25 KB -> 1 block/CU). r8/r13's proven no-spill structure:
// H0 staged in per-wave LDS, W1/W2 frag tables in LDS, one acc tile at a time.
#define OFF_W1   0
#define OFF_W2   32768
#define OFF_H0   65536                     // 8 waves x 8 ks x 64 lanes x 16 B = 65536 B
#define OFF_SELF (OFF_H0 + 65536)          // 64 nodes x 128 bf16 = 16384 B
#define OFF_WD   (OFF_SELF + NPB*HH*2)     // 256 B
#define OFF_B1   (OFF_WD + HH*2)           // 512 B (f32 b1)
#define OFF_B2   (OFF_B1 + HH*4)           // 512 B (f32 b2)
#define LDS_TOTAL (OFF_B2 + HH*4)          // 148736 B

#define MFMA(a,b,c) __builtin_amdgcn_mfma_f32_32x32x16_bf16(a,b,c,0,0,0)

// cheap bf16 pair pack: +0x8000 round-to-nearest + v_perm (3 VALU vs ~13 for
// the RNE/NaN-checked __float22bfloat162_rn). Data has no NaN/Inf; tie
// direction differs from RNE by <=1 ulp - far inside tolerance.
__device__ __forceinline__ u32 pack_bf2(float lo, float hi) {
    u32 ul, uh;
    __builtin_memcpy(&ul, &lo, 4);
    __builtin_memcpy(&uh, &hi, 4);
    return __builtin_amdgcn_perm(uh + 0x8000u, ul + 0x8000u, 0x07060302u);
}
__device__ __forceinline__ short f2bfs(float v) {
    __hip_bfloat16 h = __float2bfloat16(v);
    short r; __builtin_memcpy(&r, &h, 2); return r;
}
__device__ __forceinline__ float bf2f(short s) {
    u32 u = ((u32)(unsigned short)s) << 16;
    float f; __builtin_memcpy(&f, &u, 4); return f;
}
// tanh-form GELU: max abs err ~3e-4 vs exact erf form (well under tolerance)
__device__ __forceinline__ float gelu_t(float x) {
    float x2 = x * x;
    float t = x * fmaf(0.10294828f, x2, 2.30220913f);  // 2u*log2(e)
    float e = exp2f(t);
    float r = __builtin_amdgcn_rcpf(e + 1.0f);
    return fmaf(-x, r, x);                              // x * (1 - 1/(e+1))
}

union frag { bf16x8 v; u32 w[4]; };

// ---------------------------------------------------------------------------
// Kernel A: Ysrc = bf16((enc*mask) @ W0[0:128]), Yself = bf16(.. @ W0[128:256] + b0)
// ---------------------------------------------------------------------------
__global__ __launch_bounds__(128) void precompute_kernel(
    const float* __restrict__ enc, const float* __restrict__ mask,
    const float* __restrict__ W0, const float* __restrict__ b0,
    __hip_bfloat16* __restrict__ Ysrc, __hip_bfloat16* __restrict__ Yself)
{
    const int tid = threadIdx.x;
    const int wave = tid >> 6;
    const int lane = tid & 63;
    const int li = lane & 31;
    const int hi = lane >> 5;
    const int rowBase = blockIdx.x * 64 + wave * 32;
    const int myrow = rowBase + li;

    const float m = mask[myrow];
    bf16x8 A[8];
    #pragma unroll
    for (int ks = 0; ks < 8; ++ks) {
        const float* p = enc + (size_t)myrow * HH + ks * 16 + hi * 8;
        float4 a = *(const float4*)p;
        float4 c = *(const float4*)(p + 4);
        frag f;
        f.w[0] = pack_bf2(a.x * m, a.y * m);
        f.w[1] = pack_bf2(a.z * m, a.w * m);
        f.w[2] = pack_bf2(c.x * m, c.y * m);
        f.w[3] = pack_bf2(c.z * m, c.w * m);
        A[ks] = f.v;
    }

    #pragma unroll
    for (int h2 = 0; h2 < 2; ++h2) {
        __hip_bfloat16* dest = h2 ? Yself : Ysrc;
        #pragma unroll 1
        for (int mt = 0; mt < 4; ++mt) {
            const float bias = h2 ? b0[mt * 32 + li] : 0.0f;
            f32x16 acc;
            #pragma unroll
            for (int r = 0; r < 16; ++r) acc[r] = 0.f;
            #pragma unroll
            for (int ks = 0; ks < 8; ++ks) {
                bf16x8 Bf;
                #pragma unroll
                for (int j = 0; j < 8; ++j) {
                    int k = ks * 16 + hi * 8 + j;
                    Bf[j] = f2bfs(W0[(size_t)(h2 * HH + k) * HH + mt * 32 + li]);
                }
                acc = MFMA(A[ks], Bf, acc);
            }
            #pragma unroll
            for (int r = 0; r < 16; ++r) {
                int rrow = (r & 3) + 8 * (r >> 2) + 4 * hi;
                dest[(size_t)(rowBase + rrow) * HH + mt * 32 + li] =
                    __float2bfloat16(acc[r] + bias);
            }
        }
    }
}

// ---------------------------------------------------------------------------
// Kernel B: per-edge MLP + masked mean + fused per-block stats partials.
// r13's no-spill structure (H0 in LDS, one acc tile at a time, next-node
// register prefetch) with NPB=64 (grid 256 = 1 block/CU, single round).
// ---------------------------------------------------------------------------
__global__ __launch_bounds__(THREADS) void mpnn_kernel(
    const float* __restrict__ enc, const float* __restrict__ mask,
    const float* __restrict__ dist, const int* __restrict__ eidx,
    const __hip_bfloat16* __restrict__ Ysrc, const __hip_bfloat16* __restrict__ Yself,
    const float* __restrict__ W0,
    const float* __restrict__ W1, const float* __restrict__ b1,
    const float* __restrict__ W2, const float* __restrict__ b2,
    float* __restrict__ upd, float* __restrict__ psum2, float* __restrict__ psumsq2)
{
    extern __shared__ char lds[];
    const int tid  = threadIdx.x;
    const int wave = tid >> 6;
    const int lane = tid & 63;
    const int li   = lane & 31;
    const int hi   = lane >> 5;
    const int nodeBase = blockIdx.x * NPB;

    // ---- stage W1/W2 fragment tables (bf16, MFMA frag layout) ----
    #pragma unroll
    for (int tbl = 0; tbl < 2; ++tbl) {
        const float* W = tbl ? W2 : W1;
        short* dst = (short*)(lds + tbl * 32768);
        #pragma unroll
        for (int i = 0; i < (HH * HH) / THREADS; ++i) {
            int e = i * THREADS + tid;
            int feat = e & 127, k = e >> 7;
            float v = W[(size_t)k * HH + feat];
            int mt = feat >> 5, ks = k >> 4, h2 = (k >> 3) & 1, j = k & 7;
            dst[((mt * 8 + ks) * 64 + h2 * 32 + (feat & 31)) * 8 + j] = f2bfs(v);
        }
    }
    {
        uint4* sv = (uint4*)(lds + OFF_SELF);
        sv[tid]       = *(const uint4*)(Yself + (size_t)nodeBase * HH + tid * 8);
        sv[tid + 512] = *(const uint4*)(Yself + (size_t)nodeBase * HH + (tid + 512) * 8);
    }
    short* swd = (short*)(lds + OFF_WD);
    if (tid < HH) swd[tid] = f2bfs(W0[(size_t)256 * HH + tid]);
    float* s_b1f = (float*)(lds + OFF_B1);
    if (tid < HH) s_b1f[tid] = b1[tid];
    float* s_b2f = (float*)(lds + OFF_B2);
    if (tid < HH) s_b2f[tid] = b2[tid];
    __syncthreads();

    const int b = nodeBase >> 12;
    const __hip_bfloat16* YsB = Ysrc + (size_t)b * NN * HH;
    // per-wave H0 staging buffer: [ks][lane] x 16 B
    char* h0buf = lds + OFF_H0 + (size_t)wave * 8 * 64 * 16;

    // fused-stats accumulators for this thread's two fixed features
    float st_s0 = 0.f, st_q0 = 0.f, st_s1 = 0.f, st_q1 = 0.f;

    // ---- prologue: gather + meta for first node ----
    const int node0 = wave * NPI;
    int   ie = eidx[(size_t)(nodeBase + node0) * KK + li];
    float dd = dist[(size_t)(nodeBase + node0) * KK + li];
    float mk = mask[nodeBase + node0];
    bf16x8 g[8];
    {
        int ic0 = ie < 0 ? 0 : ie;
        const char* gb = (const char*)(YsB + (size_t)ic0 * HH) + hi * 16;
        #pragma unroll
        for (int ks = 0; ks < 8; ++ks) g[ks] = *(const bf16x8*)(gb + ks * 32);
    }

    #pragma unroll 1
    for (int i = 0; i < NPI; ++i) {
        const int node_local = node0 + i;
        const int gnode = nodeBase + node_local;

        // snapshot current node's scalars before prefetch overwrites them
        bool valid = ie >= 0;
        u32 vmask = (u32)__ballot(valid);
        int vc = __popc(vmask);
        float inv_vc = 1.0f / (float)(vc < 1 ? 1 : vc);
        float dste = dd;
        float mask_n = mk;

        // ---- layer 0: elementwise add/gelu -> H0 to LDS (g dies here) ----
        const short* sself = (const short*)(lds + OFF_SELF) + node_local * HH;
        #pragma unroll
        for (int ks = 0; ks < 8; ++ks) {
            bf16x8 ys = *(const bf16x8*)(sself + ks * 16 + hi * 8);
            bf16x8 wd = *(const bf16x8*)(swd + ks * 16 + hi * 8);
            frag h;
            #pragma unroll
            for (int q = 0; q < 4; ++q) {
                float f0 = gelu_t(bf2f(g[ks][2*q])   + bf2f(ys[2*q])   + dste * bf2f(wd[2*q]));
                float f1 = gelu_t(bf2f(g[ks][2*q+1]) + bf2f(ys[2*q+1]) + dste * bf2f(wd[2*q+1]));
                h.w[q] = pack_bf2(f0, f1);
            }
            *(bf16x8*)(h0buf + (ks * 64 + lane) * 16) = h.v;
        }

        // ---- prefetch next node's gather + meta (hides under layers 1-2) ----
        if (i + 1 < NPI) {
            ie = eidx[(size_t)(gnode + 1) * KK + li];
            dd = dist[(size_t)(gnode + 1) * KK + li];
            mk = mask[gnode + 1];
            int icn = ie < 0 ? 0 : ie;
            const char* gb = (const char*)(YsB + (size_t)icn * HH) + hi * 16;
            #pragma unroll
            for (int ks = 0; ks < 8; ++ks) g[ks] = *(const bf16x8*)(gb + ks * 32);
        }

        // ---- layer 1 (transposed): per mt-tile, B re-read from LDS ----
        frag F2[8];
        #pragma unroll
        for (int mt = 0; mt < 4; ++mt) {
            f32x16 acc;
            #pragma unroll
            for (int r = 0; r < 16; ++r) acc[r] = 0.f;
            #pragma unroll
            for (int ks = 0; ks < 8; ++ks) {
                bf16x8 a = *(const bf16x8*)(lds + OFF_W1 + ((mt * 8 + ks) * 64 + lane) * 16);
                bf16x8 h0 = *(const bf16x8*)(h0buf + (ks * 64 + lane) * 16);
                acc = MFMA(a, h0, acc);
            }
            u32 pk8[8];
            #pragma unroll
            for (int q = 0; q < 8; ++q) {
                int row0 = 8 * (q >> 1) + 2 * (q & 1) + 4 * hi;   // rows row0,row0+1
                float2 bb = *(const float2*)(s_b1f + mt * 32 + row0);
                pk8[q] = pack_bf2(gelu_t(acc[2*q] + bb.x), gelu_t(acc[2*q+1] + bb.y));
            }
            #pragma unroll
            for (int e = 0; e < 2; ++e) {
                const int ks = 2 * mt + e;
                #pragma unroll
                for (int r = 0; r < 4; ++r) {
                    const int q0 = (r & 1) + 4 * e;
                    u32 own  = hi ? pk8[q0 + 2] : pk8[q0];
                    u32 give = hi ? pk8[q0]     : pk8[q0 + 2];
                    u32 got  = (u32)__shfl_xor((int)give, 32, 64);
                    F2[ks].w[r] = ((r >> 1) == hi) ? own : got;
                }
            }
        }

        // ---- layer 2 (normal), one nt-tile at a time -> scalars ----
        float s0, s1, s2, s3;
        #pragma unroll
        for (int nt = 0; nt < 4; ++nt) {
            f32x16 acc;
            #pragma unroll
            for (int r = 0; r < 16; ++r) acc[r] = 0.f;
            #pragma unroll
            for (int ks = 0; ks < 8; ++ks) {
                bf16x8 w2f = *(const bf16x8*)(lds + OFF_W2 + ((nt * 8 + ks) * 64 + lane) * 16);
                acc = MFMA(F2[ks].v, w2f, acc);
            }
            float bv = s_b2f[nt * 32 + li];
            float t = 0.f;
            #pragma unroll
            for (int r = 0; r < 16; ++r) {
                float v = gelu_t(acc[r] + bv);
                int edge = (r & 3) + 8 * (r >> 2) + 4 * hi;
                t += ((vmask >> edge) & 1) ? v : 0.f;
            }
            t += __shfl_xor(t, 32, 64);
            if (nt == 0) s0 = t; else if (nt == 1) s1 = t;
            else if (nt == 2) s2 = t; else s3 = t;
        }

        // ---- epilogue: thread writes feats (hi*2)*32+li and (hi*2+1)*32+li ----
        float sa = hi ? s2 : s0;
        float sb = hi ? s3 : s1;
        int f0 = (hi * 2) * 32 + li;
        int f1 = (hi * 2 + 1) * 32 + li;
        float u0 = (enc[(size_t)gnode * HH + f0] + sa * inv_vc) * mask_n;
        float u1 = (enc[(size_t)gnode * HH + f1] + sb * inv_vc) * mask_n;
        upd[(size_t)gnode * HH + f0] = u0;
        upd[(size_t)gnode * HH + f1] = u1;
        st_s0 += u0; st_q0 = fmaf(u0, u0, st_q0);
        st_s1 += u1; st_q1 = fmaf(u1, u1, st_q1);
    }

    // ---- fused stats: block-level partials per feature (reuses H0 region) ----
    __syncthreads();
    float4* red = (float4*)(lds + OFF_H0);
    red[tid] = make_float4(st_s0, st_q0, st_s1, st_q1);
    __syncthreads();
    if (tid < HH) {
        const int f = tid;
        const int q = f >> 5;
        const int rl = (q >> 1) * 32 + (f & 31);  // lane within each wave
        const bool use1 = (q & 1) != 0;
        float s = 0.f, sq = 0.f;
        #pragma unroll
        for (int w = 0; w < 8; ++w) {
            float4 v = red[w * 64 + rl];
            s  += use1 ? v.z : v.x;
            sq += use1 ? v.w : v.y;
        }
        psum2[(size_t)blockIdx.x * HH + f]   = s;
        psumsq2[(size_t)blockIdx.x * HH + f] = sq;
    }
}

// ---------------------------------------------------------------------------
// Kernel 2b: combine per-block partials -> mean, 1/std per (b, feature)
// ---------------------------------------------------------------------------
__global__ __launch_bounds__(128) void finalize_stats_kernel(
    const float* __restrict__ psum2, const float* __restrict__ psumsq2,
    const float* __restrict__ mask, float* __restrict__ meanp, float* __restrict__ istdp)
{
    const int b = blockIdx.x;
    const int j = threadIdx.x;
    float s = 0.f, s2 = 0.f;
    #pragma unroll 4
    for (int c = 0; c < BPB; ++c) {
        s  += psum2[((size_t)(b * BPB + c)) * HH + j];
        s2 += psumsq2[((size_t)(b * BPB + c)) * HH + j];
    }
    float cpart = 0.f;
    #pragma unroll 4
    for (int t = 0; t < NN / HH; ++t)
        cpart += mask[(size_t)b * NN + (size_t)t * HH + j];
    __shared__ float red[HH];
    red[j] = cpart;
    __syncthreads();
    for (int off = HH / 2; off > 0; off >>= 1) {
        if (j < off) red[j] += red[j + off];
        __syncthreads();
    }
    float counts = red[0];
    if (counts == 0.f) counts = 1.f;
    float mean = s / counts;
    float var  = (s2 - 2.f * mean * s + (float)NN * mean * mean) / counts;
    meanp[b * HH + j] = mean;
    istdp[b * HH + j] = 1.0f / sqrtf(var + 1e-5f);
}

// ---------------------------------------------------------------------------
// Kernel 3: normalize out0 in place + write pass-through outputs
// ---------------------------------------------------------------------------
__global__ void write_out_kernel(
    const float* __restrict__ mask, const float* __restrict__ dist,
    const int* __restrict__ eidx, const float* __restrict__ meanp,
    const float* __restrict__ istdp, const float* __restrict__ scale,
    const float* __restrict__ shift, float* __restrict__ out)
{
    const size_t T0 = (size_t)BB * NN * HH;
    const size_t T1 = (size_t)BB * NN;
    const size_t T2 = (size_t)BB * NN * KK;
    const size_t stride = (size_t)gridDim.x * blockDim.x;
    const size_t t = (size_t)blockIdx.x * blockDim.x + threadIdx.x;

    for (size_t x = t; x < T0; x += stride) {
        int h = (int)(x & (HH - 1));
        size_t bn = x >> 7;
        int b = (int)(bn >> 12);
        float m = mask[bn];
        float v = (out[x] - meanp[b * HH + h]) * istdp[b * HH + h] * scale[h] + shift[h];
        out[x] = v * m;
    }
    float* out1 = out + T0;
    for (size_t x = t; x < T1; x += stride) out1[x] = mask[x];
    float* out2 = out1 + T1;
    for (size_t x = t; x < T2; x += stride) out2[x] = dist[x];
    float* out3 = out2 + T2;
    for (size_t x = t; x < T2; x += stride) out3[x] = (float)eidx[x];
}

// ---------------------------------------------------------------------------
extern "C" void kernel_launch(void* const* d_in, const int* in_sizes, int n_in,
                              void* d_out, int out_size, void* d_ws, size_t ws_size,
                              hipStream_t stream) {
    const float* enc   = (const float*)d_in[0];
    const float* mask  = (const float*)d_in[1];
    const float* dist  = (const float*)d_in[2];
    const int*   eidx  = (const int*)  d_in[3];
    const float* W0    = (const float*)d_in[4];
    const float* b0    = (const float*)d_in[5];
    const float* W1    = (const float*)d_in[6];
    const float* b1    = (const float*)d_in[7];
    const float* W2    = (const float*)d_in[8];
    const float* b2    = (const float*)d_in[9];
    const float* scale = (const float*)d_in[10];
    const float* shift = (const float*)d_in[11];
    float* out = (float*)d_out;
    float* upd = out;   // pre-norm upd lives in out[0:B*N*H], normalized in place later

    const size_t T0 = (size_t)BB * NN * HH;
    const size_t T1 = (size_t)BB * NN;

    __hip_bfloat16* Ysrc  = (__hip_bfloat16*)d_ws;                 // 4 MB
    __hip_bfloat16* Yself = (__hip_bfloat16*)(out + T0 + T1);      // 4 MB (out2/out3 region, overwritten last)
    float* wsf     = (float*)((char*)d_ws + (size_t)BB * NN * HH * 2);
    float* psum2   = wsf;                                          // 256*128 = 128 KB
    float* psumsq2 = psum2 + (size_t)NBLK * HH;                    // 128 KB
    float* meanp   = psumsq2 + (size_t)NBLK * HH;
    float* istdp   = meanp + (size_t)BB * HH;

    hipFuncSetAttribute((const void*)mpnn_kernel,
                        hipFuncAttributeMaxDynamicSharedMemorySize, LDS_TOTAL);

    precompute_kernel<<<dim3(256), dim3(128), 0, stream>>>(enc, mask, W0, b0, Ysrc, Yself);
    mpnn_kernel<<<dim3(NBLK), dim3(THREADS), LDS_TOTAL, stream>>>(
        enc, mask, dist, eidx, Ysrc, Yself, W0, W1, b1, W2, b2, upd, psum2, psumsq2);
    finalize_stats_kernel<<<dim3(BB), dim3(128), 0, stream>>>(psum2, psumsq2, mask, meanp, istdp);
    write_out_kernel<<<dim3(1024), dim3(256), 0, stream>>>(
        mask, dist, eidx, meanp, istdp, scale, shift, out);
}